// Round 1
// baseline (379.484 us; speedup 1.0000x reference)
//
#include <hip/hip_runtime.h>
#include <stdint.h>

// ConvolutionN: B=64, C=64, H=W=128, K=7, PAD=3, one output channel, fp32.
// v7 = single-writer restructure of v6:
//   - channel split (cs) moved INSIDE the block: 512 blocks = 64 b x 8 bands,
//     each block runs 22 pipeline units (11 row-pairs x 2 channel halves),
//     both halves accumulate into the same wave-private LDS slot accumulator.
//   - output rows are finished exactly once per pixel -> plain global store,
//     NO atomicAdd, NO hipMemsetAsync in the launch (the memset was the
//     1-GiB fillBufferAligned at ~160 us dominating the timed graph).
//   - work totals identical to v6: same 369 MB fetch, same 11,264
//     unit-executions chip-wide, same LDS (47 KB -> 3 blocks/CU capacity),
//     same barrier rate. Occupancy: 2 blocks/CU resident (grid 512).

typedef short bf16x8 __attribute__((ext_vector_type(8)));
typedef float f32x4 __attribute__((ext_vector_type(4)));

#define HB    16
#define XS    20             // dwords per col slot: 32ch bf16 = 16 dw + 4 pad
#define XCOLS 134            // cols -3..130 stored at +3
#define XB1   (XCOLS * XS)   // one row = 2680 dw
#define AROW  132            // acc row stride (dw)
#define NSLOT 8

__device__ __forceinline__ uint32_t pk2bf(float a, float b) {
    uint32_t ua = __builtin_bit_cast(uint32_t, a);
    uint32_t ub = __builtin_bit_cast(uint32_t, b);
    ua += 0x7FFFu + ((ua >> 16) & 1u);
    ub += 0x7FFFu + ((ub >> 16) & 1u);
    return (ua >> 16) | (ub & 0xFFFF0000u);
}

// LDS-only barrier: global loads stay in flight (no vmcnt(0) drain).
__device__ __forceinline__ void lds_barrier() {
    asm volatile("s_waitcnt lgkmcnt(0)\n\ts_barrier" ::: "memory");
}

// Stage pre[8] (8 ch x 4 cols fp32) as bf16 into DST row buffer.
#define STAGE(DST)                                                            \
    do {                                                                      \
        _Pragma("unroll")                                                     \
        for (int j = 0; j < 4; j++) {                                         \
            float c0 = (&pre[0].x)[j], c1 = (&pre[1].x)[j],                   \
                  c2 = (&pre[2].x)[j], c3 = (&pre[3].x)[j],                   \
                  c4 = (&pre[4].x)[j], c5 = (&pre[5].x)[j],                   \
                  c6 = (&pre[6].x)[j], c7 = (&pre[7].x)[j];                   \
            uint4 u;                                                          \
            u.x = pk2bf(c0, c1); u.y = pk2bf(c2, c3);                         \
            u.z = pk2bf(c4, c5); u.w = pk2bf(c6, c7);                         \
            *(uint4*)&(DST)[rsel * XB1 + (4 * colq + j + 3) * XS + 4 * cgrp] = u; \
        }                                                                     \
    } while (0)

// Issue global loads for row-pair RK (rows r0+2*RK+rsel) from base pointer XP.
#define LOADPRE(XP, RK)                                                       \
    do {                                                                      \
        const int rn    = r0 + 2 * (RK) + rsel;                               \
        const bool vn   = ((unsigned)rn < 128u);                              \
        const int basen = rn * 32 + colq;                                     \
        _Pragma("unroll")                                                     \
        for (int i = 0; i < 8; i++) {                                         \
            float4 g = {0.f, 0.f, 0.f, 0.f};                                  \
            if (vn) g = (XP)[i * 4096 + basen];                               \
            pre[i] = g;                                                       \
        }                                                                     \
    } while (0)

// MFMA both rows of the pair from BUF with fragments BF, accumulate guarded.
#define MFMA_UNIT(BUF, BF)                                                    \
    do {                                                                      \
        _Pragma("unroll")                                                     \
        for (int sub = 0; sub < 2; sub++) {                                   \
            const int r = r0 + 2 * k2 + sub;                                  \
            f32x4 a0 = {0.f, 0.f, 0.f, 0.f};                                  \
            f32x4 a1 = {0.f, 0.f, 0.f, 0.f};                                  \
            const uint32_t* rowbuf = (BUF) + sub * XB1;                       \
            _Pragma("unroll")                                                 \
            for (int kk = 0; kk < 7; kk++) {                                  \
                const uint32_t* ap = &rowbuf[(32 * wv + nl + kk) * XS + 4 * q]; \
                uint4 A0 = *(const uint4*)ap;                                 \
                uint4 A1 = *(const uint4*)(ap + 16 * XS);                     \
                a0 = __builtin_amdgcn_mfma_f32_16x16x32_bf16(                 \
                         __builtin_bit_cast(bf16x8, A0), (BF)[kk], a0, 0, 0, 0); \
                a1 = __builtin_amdgcn_mfma_f32_16x16x32_bf16(                 \
                         __builtin_bit_cast(bf16x8, A1), (BF)[kk], a1, 0, 0, 0); \
            }                                                                 \
            /* P[r, ow, dh=nl] -> acc slot oh&7, oh = r+3-nl; in-band only */ \
            if (nl < 7) {                                                     \
                const int oh = r + 3 - nl;                                    \
                if ((unsigned)(oh - h0) < (unsigned)HB) {                     \
                    const int s = oh & 7;                                     \
                    float* p0 = &acc[s * AROW + 32 * wv + 4 * q];             \
                    f32x4 c0 = *(f32x4*)p0;                                   \
                    f32x4 c1 = *(f32x4*)(p0 + 16);                            \
                    _Pragma("unroll")                                         \
                    for (int j = 0; j < 4; j++) { c0[j] += a0[j]; c1[j] += a1[j]; } \
                    *(f32x4*)p0 = c0;                                         \
                    *(f32x4*)(p0 + 16) = c1;                                  \
                }                                                             \
            }                                                                 \
        }                                                                     \
    } while (0)

__global__ __launch_bounds__(256, 2)
void conv_v7(const float* __restrict__ x, const float* __restrict__ w,
             const float* __restrict__ bias, float* __restrict__ out) {
    __shared__ uint32_t xlds[2][2 * XB1];      // 42880 B
    __shared__ float    acc[NSLOT * AROW];     // 4224 B

    const int tid  = threadIdx.x;
    const int lane = tid & 63;
    const int wv   = tid >> 6;                 // wave -> ow cols 32wv..32wv+31
    const int bx   = blockIdx.x;
    const int band = bx & 7;
    const int b    = bx >> 3;
    const int h0   = band * HB;
    const int r0   = h0 - 3;

    const int nl = lane & 15;
    const int q  = lane >> 4;

    // ---- zero acc + halo cols (cols 0,1,2,131,132,133 of both rows/bufs) ----
    for (int i = tid; i < NSLOT * AROW; i += 256) acc[i] = 0.f;
    for (int i = tid; i < 2 * 2 * 6 * XS; i += 256) {
        int bi   = i / (2 * 6 * XS);
        int rem  = i - bi * (2 * 6 * XS);
        int rs   = rem / (6 * XS);
        int rem2 = rem - rs * (6 * XS);
        int colh = rem2 / XS;
        int dwi  = rem2 - colh * XS;
        int col  = (colh < 3) ? colh : (128 + colh);
        xlds[bi][rs * XB1 + col * XS + dwi] = 0u;
    }

    // ---- B fragments for BOTH halves: Bf?[dw][k=8q+j][n=nl] ----
    bf16x8 Bf0[7], Bf1[7];
#pragma unroll
    for (int kk = 0; kk < 7; kk++) {
        bf16x8 f0, f1;
#pragma unroll
        for (int j = 0; j < 8; j++) {
            float v0 = (nl < 7) ? w[(8 * q + j) * 49 + nl * 7 + kk] : 0.f;
            float v1 = (nl < 7) ? w[(32 + 8 * q + j) * 49 + nl * 7 + kk] : 0.f;
            uint32_t u0 = __builtin_bit_cast(uint32_t, v0);
            uint32_t u1 = __builtin_bit_cast(uint32_t, v1);
            u0 += 0x7FFFu + ((u0 >> 16) & 1u);
            u1 += 0x7FFFu + ((u1 >> 16) & 1u);
            f0[j] = (short)(u0 >> 16);
            f1[j] = (short)(u1 >> 16);
        }
        Bf0[kk] = f0;
        Bf1[kk] = f1;
    }

    // ---- staging geometry: thread stages 8 ch x 4 cols of ONE row of a pair
    const int cgrp = tid & 3;                  // ch base 8*cgrp (half-local)
    const int rsel = tid >> 7;                 // which row of the pair
    const int colq = (tid >> 2) & 31;          // col quad 0..31
    const float4* xp0 = (const float4*)x + ((size_t)b * 64 + 8 * cgrp) * 4096;
    const float4* xp1 = xp0 + 32 * 4096;       // channel half 1

    float4 pre[8];

    // ---- prologue: unit0 (cs=0, rows k2=0) load+stage; unit1 (cs=1) load ----
    {
        const int r    = r0 + rsel;
        const bool v   = ((unsigned)r < 128u);
        const int base = r * 32 + colq;
#pragma unroll
        for (int i = 0; i < 8; i++) {
            float4 g = {0.f, 0.f, 0.f, 0.f};
            if (v) g = xp0[i * 4096 + base];
            pre[i] = g;
        }
        STAGE(xlds[0]);
#pragma unroll
        for (int i = 0; i < 8; i++) {
            float4 g = {0.f, 0.f, 0.f, 0.f};
            if (v) g = xp1[i * 4096 + base];
            pre[i] = g;
        }
    }
    lds_barrier();

    const float bv = bias[0];

#pragma unroll 1
    for (int k2 = 0; k2 < 11; k2++) {
        // ======== body A: unit 2*k2 (cs=0), data in xlds[0] ========
        MFMA_UNIT(xlds[0], Bf0);
        STAGE(xlds[1]);                        // unit 2k2+1 (cs=1, rows k2)
        if (k2 <= 9) LOADPRE(xp0, k2 + 1);     // unit 2k2+2 (cs=0, rows k2+1)
        lds_barrier();

        // ======== body B: unit 2*k2+1 (cs=1), data in xlds[1] ========
        MFMA_UNIT(xlds[1], Bf1);

        // finalize rows oh = h0 + 2k2-6 (+1): both halves now accumulated.
        if (k2 >= 3) {
            const int oh  = h0 + 2 * k2 - 6 + (lane >> 5);
            const int col = 32 * wv + (lane & 31);
            float* ap = &acc[(oh & 7) * AROW + col];
            float v = *ap + bv;
            *ap = 0.f;                         // reset before slot reuse (oh+8)
            out[(size_t)b * 16384 + (size_t)oh * 128 + col] = v;  // plain store
        }

        if (k2 <= 9) {
            STAGE(xlds[0]);                    // unit 2k2+2 (cs=0, rows k2+1)
            LOADPRE(xp1, k2 + 1);              // unit 2k2+3 (cs=1, rows k2+1)
        }
        lds_barrier();
    }
}

extern "C" void kernel_launch(void* const* d_in, const int* in_sizes, int n_in,
                              void* d_out, int out_size, void* d_ws, size_t ws_size,
                              hipStream_t stream) {
    const float* x    = (const float*)d_in[0];   // (64,64,128,128)
    const float* w    = (const float*)d_in[1];   // (64,7,7)
    const float* bias = (const float*)d_in[2];   // (1,)
    float* out        = (float*)d_out;           // (64,128,128)

    // No memset: every output element is written exactly once by conv_v7.
    hipLaunchKernelGGL(conv_v7, dim3(512), dim3(256), 0, stream, x, w, bias, out);
}

// Round 3
// 376.933 us; speedup vs baseline: 1.0068x; 1.0068x over previous
//
#include <hip/hip_runtime.h>
#include <stdint.h>

// ConvolutionN: B=64, C=64, H=W=128, K=7, PAD=3, one output channel, fp32.
// v8 (resubmit; round-2 failure was a container-infra flake, not the kernel)
// = v6 structure (cs-split blocks + atomicAdd finalize, proven-fastest
// occupancy) with DOUBLED band height to cut halo over-fetch:
//   - HB=32: 38 rows fetched per 32-row band -> 318 MB total (v6/v7: 369 MB)
//   - grid 512 = 64 b x 4 bands x 2 cs; 512 threads = 8 waves; 2 blocks/CU
//     resident -> 16 waves/CU (v6: 12, v7: 8)
//   - each wave owns a 16-col output strip (one 16x16x32 MFMA tile per row)
//   - staging: thread loads 4 ch x 4 cols (pre[4] float4), packs bf16,
//     ds_write_b64; one lgkm-only barrier per row-pair, loads 2 pairs ahead
//   - wave-private 8-slot LDS accumulator ring (slot = oh&7), in-band guard
//   - fp32 atomicAdd finalize (2 cs halves) + 4 MB memset (~0.6 us in-graph)

typedef short bf16x8 __attribute__((ext_vector_type(8)));
typedef float f32x4 __attribute__((ext_vector_type(4)));

#define HB    32
#define NPAIR 19            // rows r0..r0+37 = h0-3 .. h0+34
#define XS    20            // dwords per col slot: 32ch bf16 = 16 dw + 4 pad
#define XCOLS 134           // cols -3..130 stored at +3
#define XB1   (XCOLS * XS)  // one row = 2680 dw
#define AROW  132           // acc row stride (dw)
#define NSLOT 8

__device__ __forceinline__ uint32_t pk2bf(float a, float b) {
    uint32_t ua = __builtin_bit_cast(uint32_t, a);
    uint32_t ub = __builtin_bit_cast(uint32_t, b);
    ua += 0x7FFFu + ((ua >> 16) & 1u);
    ub += 0x7FFFu + ((ub >> 16) & 1u);
    return (ua >> 16) | (ub & 0xFFFF0000u);
}

// LDS-only barrier: global loads stay in flight (no vmcnt(0) drain).
__device__ __forceinline__ void lds_barrier() {
    asm volatile("s_waitcnt lgkmcnt(0)\n\ts_barrier" ::: "memory");
}

// Stage pre[4] (4 ch x 4 cols fp32) as bf16 into DST row buffer (b64 writes).
#define STAGE(DST)                                                            \
    do {                                                                      \
        _Pragma("unroll")                                                     \
        for (int j = 0; j < 4; j++) {                                         \
            float c0 = (&pre[0].x)[j], c1 = (&pre[1].x)[j],                   \
                  c2 = (&pre[2].x)[j], c3 = (&pre[3].x)[j];                   \
            uint2 u;                                                          \
            u.x = pk2bf(c0, c1);                                              \
            u.y = pk2bf(c2, c3);                                              \
            *(uint2*)&(DST)[rsel * XB1 + (4 * colq + j + 3) * XS + 2 * cgrp] = u; \
        }                                                                     \
    } while (0)

// Issue global loads for row-pair RK (rows r0+2*RK+rsel) into pre[4].
#define LOADPRE(RK)                                                           \
    do {                                                                      \
        const int rn    = r0 + 2 * (RK) + rsel;                               \
        const bool vn   = ((unsigned)rn < 128u);                              \
        const int basen = rn * 32 + colq;                                     \
        _Pragma("unroll")                                                     \
        for (int i = 0; i < 4; i++) {                                         \
            float4 g = {0.f, 0.f, 0.f, 0.f};                                  \
            if (vn) g = xp4[i * 4096 + basen];                                \
            pre[i] = g;                                                       \
        }                                                                     \
    } while (0)

__global__ __launch_bounds__(512, 4)
void conv_v8(const float* __restrict__ x, const float* __restrict__ w,
             const float* __restrict__ bias, float* __restrict__ out) {
    __shared__ uint32_t xlds[2][2 * XB1];      // 42880 B
    __shared__ float    acc[NSLOT * AROW];     // 4224 B

    const int tid  = threadIdx.x;
    const int lane = tid & 63;
    const int wv   = tid >> 6;                 // wave -> ow cols 16wv..16wv+15
    const int bx   = blockIdx.x;
    const int cs   = bx & 1;                   // channel half
    const int band = (bx >> 1) & 3;
    const int b    = bx >> 3;
    const int h0   = band * HB;
    const int r0   = h0 - 3;

    const int nl = lane & 15;
    const int q  = lane >> 4;

    // ---- zero acc + halo cols (cols 0,1,2,131,132,133 of both rows/bufs) ----
    for (int i = tid; i < NSLOT * AROW; i += 512) acc[i] = 0.f;
    for (int i = tid; i < 2 * 2 * 6 * XS; i += 512) {
        int bi   = i / (2 * 6 * XS);
        int rem  = i - bi * (2 * 6 * XS);
        int rs   = rem / (6 * XS);
        int rem2 = rem - rs * (6 * XS);
        int colh = rem2 / XS;
        int dwi  = rem2 - colh * XS;
        int col  = (colh < 3) ? colh : (128 + colh);
        xlds[bi][rs * XB1 + col * XS + dwi] = 0u;
    }

    // ---- B fragments: Bf[dw][k=8q+j][n=nl] = w_bf16[32cs+8q+j, dh=nl, dw] ----
    bf16x8 Bf[7];
#pragma unroll
    for (int kk = 0; kk < 7; kk++) {
        bf16x8 f;
#pragma unroll
        for (int j = 0; j < 8; j++) {
            float v = (nl < 7) ? w[(32 * cs + 8 * q + j) * 49 + nl * 7 + kk] : 0.f;
            uint32_t u = __builtin_bit_cast(uint32_t, v);
            u += 0x7FFFu + ((u >> 16) & 1u);
            f[j] = (short)(u >> 16);
        }
        Bf[kk] = f;
    }

    // ---- staging geometry: thread stages 4 ch x 4 cols of ONE row of a pair
    const int cgrp = tid & 7;                  // ch base 4*cgrp (half-local)
    const int colq = (tid >> 3) & 31;          // col quad 0..31
    const int rsel = tid >> 8;                 // which row of the pair
    const float4* xp4 =
        (const float4*)x + ((size_t)b * 64 + 32 * cs + 4 * cgrp) * 4096;

    float4 pre[4];

    // ---- prologue: pair0 load+stage, pair1 load, barrier ----
    LOADPRE(0);
    STAGE(xlds[0]);
    LOADPRE(1);
    lds_barrier();

    const float bv = (cs == 0) ? bias[0] : 0.f;

#pragma unroll 1
    for (int k = 0; k < NPAIR; k++) {
        const uint32_t* buf = xlds[k & 1];

        // ---- MFMA + accumulate both rows of the pair (one 16-col tile) ----
#pragma unroll
        for (int sub = 0; sub < 2; sub++) {
            const int r = r0 + 2 * k + sub;
            f32x4 a0 = {0.f, 0.f, 0.f, 0.f};
            const uint32_t* rowbuf = buf + sub * XB1;
#pragma unroll
            for (int kk = 0; kk < 7; kk++) {
                const uint32_t* ap = &rowbuf[(16 * wv + nl + kk) * XS + 4 * q];
                uint4 A0 = *(const uint4*)ap;
                a0 = __builtin_amdgcn_mfma_f32_16x16x32_bf16(
                         __builtin_bit_cast(bf16x8, A0), Bf[kk], a0, 0, 0, 0);
            }
            // P[r, ow=16wv+4q+j, dh=nl] -> acc slot oh&7, oh = r+3-nl.
            // In-band guard: out-of-band oh belongs to the neighboring band.
            if (nl < 7) {
                const int oh = r + 3 - nl;
                if ((unsigned)(oh - h0) < (unsigned)HB) {
                    const int s = oh & 7;
                    float* p0 = &acc[s * AROW + 16 * wv + 4 * q];
                    f32x4 c0 = *(f32x4*)p0;
#pragma unroll
                    for (int j = 0; j < 4; j++) c0[j] += a0[j];
                    *(f32x4*)p0 = c0;
                }
            }
        }

        // ---- finalize rows oh = h0+2k-6 (+1): all contributions now in ----
        if (k >= 3 && lane < 32) {
            const int oh  = h0 + 2 * k - 6 + (lane >> 4);
            const int col = 16 * wv + (lane & 15);
            float* ap = &acc[(oh & 7) * AROW + col];
            float v = *ap + bv;
            *ap = 0.f;                         // reset before slot reuse (oh+8)
            atomicAdd(&out[(size_t)b * 16384 + (size_t)oh * 128 + col], v);
        }

        // ---- stage pair k+1 (other buffer), then issue loads pair k+2 ----
        if (k <= NPAIR - 2) {
            STAGE(xlds[(k + 1) & 1]);
            if (k <= NPAIR - 3) LOADPRE(k + 2);
        }

        // ---- one LDS-only barrier per pair ----
        lds_barrier();
    }
}

extern "C" void kernel_launch(void* const* d_in, const int* in_sizes, int n_in,
                              void* d_out, int out_size, void* d_ws, size_t ws_size,
                              hipStream_t stream) {
    const float* x    = (const float*)d_in[0];   // (64,64,128,128)
    const float* w    = (const float*)d_in[1];   // (64,7,7)
    const float* bias = (const float*)d_in[2];   // (1,)
    float* out        = (float*)d_out;           // (64,128,128)

    hipMemsetAsync(d_out, 0, (size_t)out_size * sizeof(float), stream);
    hipLaunchKernelGGL(conv_v8, dim3(512), dim3(512), 0, stream, x, w, bias, out);
}